// Round 14
// baseline (93.501 us; speedup 1.0000x reference)
//
#include <hip/hip_runtime.h>

#define T_ 4
#define B_ 8
#define C_ 256
#define TB_ 32
#define SQRT2_ 1.4142135623730951
#define INVS2_ 0.7071067811865475
#define EPS_ 1e-5

typedef __attribute__((ext_vector_type(8))) short short8;
typedef __attribute__((ext_vector_type(4))) float f32x4;

// ---- workspace layout ----
#define XST_OFF  ((size_t)0)           // bf16 xsT [tb][nb][pos1024][d16]  16 MB
#define H1C_OFF  ((size_t)16777216)    // i8 h1 codes                       8 MB
#define COEF_OFF ((size_t)25165824)    // bf16 coef dumps                  16 MB
#define ST_OFF   ((size_t)41943040)    // doubles stats, 16 reps x 4608 (S3..S5 used)
#define WTAB_OFF ((size_t)42532864)    // convW 6KB + mixW 16KB
#define HIST_OFF ((size_t)42555392)    // int hist[64rep][20bin][256c]  1.25MB
#define S3S 3072
#define S3Q 3328
#define S4S 3584
#define S4Q 3840
#define S5S 4096
#define S5Q 4352
#define NST 4608
#define NREP 16
#define NHREP 64

__device__ __forceinline__ unsigned short f2bf(float v) {
    union { float f; unsigned u; } x; x.f = v;
    unsigned r = x.u + 0x7FFFu + ((x.u >> 16) & 1u);
    return (unsigned short)(r >> 16);
}

__device__ __forceinline__ double st_sum(const double* __restrict__ st, int idx) {
    double s = 0.0;
    #pragma unroll
    for (int r = 0; r < NREP; ++r) s += st[r * NST + idx];
    return s;
}

// ---- fragment builders (k1 block 0 only) ----
__device__ __forceinline__ void mix_frags_q(const float* __restrict__ hw, int gbq, int lane, short8 am[4]) {
    const int o = lane & 15, g = lane >> 4;
    #pragma unroll
    for (int q = 0; q < 4; ++q) {
        #pragma unroll
        for (int e = 0; e < 8; ++e) {
            const int kk = g * 8 + e;
            unsigned short v = 0;
            if ((kk >> 4) == (q & 1)) {
                const int d = kk & 15;
                const int nbp = q * 4 + gbq;
                v = f2bf(hw[(nbp * 16 + d) * 16 + o]);
            }
            am[q][e] = (short)v;
        }
    }
}

__device__ __forceinline__ void conv_frags(const float* __restrict__ w1, const float* __restrict__ w2w,
                                           int lane, short8* awc2, short8& awc1) {
    const int o = lane & 15, g = lane >> 4, dA = (g & 1) * 8;
    #pragma unroll
    for (int m = 0; m < 5; ++m) {
        const int t = (m < 4) ? (2 * m + (g >> 1)) : 8;
        const bool act = (m < 4) || (g < 2);
        #pragma unroll
        for (int j = 0; j < 8; ++j) {
            const float wv = act ? w2w[(o * 16 + dA + j) * 9 + t] : 0.0f;
            awc2[m][j] = (short)f2bf(wv);
        }
    }
    #pragma unroll
    for (int j = 0; j < 8; ++j) {
        const float wv = (g < 2) ? w1[o * 16 + dA + j] : 0.0f;
        awc1[j] = (short)f2bf(wv);
    }
}

__device__ __forceinline__ void load_conv_frags(const unsigned short* __restrict__ convW,
                                                int lane, short8* awc2, short8& awc1) {
    #pragma unroll
    for (int m = 0; m < 5; ++m) awc2[m] = *(const short8*)&convW[(m * 64 + lane) * 8];
    awc1 = *(const short8*)&convW[(5 * 64 + lane) * 8];
}
__device__ __forceinline__ void load_mix_frags(const unsigned short* __restrict__ mixW,
                                               int gbq, int lane, short8 am[4]) {
    #pragma unroll
    for (int q = 0; q < 4; ++q) am[q] = *(const short8*)&mixW[((gbq * 4 + q) * 64 + lane) * 8];
}

// ============ K1: LIF (fp64) -> xsT, h1c, exclusive-slot histograms (1024 blocks) ============
// block = (b, nb, qh: 4-row band); thread d(16) x pg(16): row qh*4+(pg>>2), cols (pg&3)*8..+8
__global__ __launch_bounds__(256) void k1_lif(const float* __restrict__ x,
                                              unsigned short* __restrict__ xsT,
                                              signed char* __restrict__ h1c,
                                              int* __restrict__ hist,
                                              double* __restrict__ st,
                                              const float* __restrict__ w1, const float* __restrict__ w2w,
                                              const float* __restrict__ hw,
                                              unsigned short* __restrict__ convW,
                                              unsigned short* __restrict__ mixW) {
    const int qh = blockIdx.x & 7, nb = (blockIdx.x >> 3) & 15, b = blockIdx.x >> 7;
    const int tid = threadIdx.x;
    if (tid < 36) {     // distributed zeroing of st (73728 doubles over 1024 blocks)
        double2 z2; z2.x = 0.0; z2.y = 0.0;
        *(double2*)(st + (size_t)blockIdx.x * 72 + tid * 2) = z2;
    }
    const int d = tid >> 4, pg = tid & 15;
    const int c = nb * 16 + d;
    const int r = qh * 4 + (pg >> 2);
    const int cseg = (pg & 3) * 8;
    __shared__ __align__(16) char tr[16384];   // 4 t-slices x [d16][pos128] ushort
    double v[8];
    #pragma unroll
    for (int i = 0; i < 8; ++i) v[i] = 0.0;
    unsigned long long cs = 0, cdd = 0, cu = 0, cv = 0;
    #pragma unroll
    for (int t = 0; t < T_; ++t) {
        const size_t xi = ((size_t)((t * 8 + b) * 256 + c)) * 1024 + r * 32 + cseg;
        const float4* xp = (const float4*)(x + xi);
        int sp[8];
        #pragma unroll
        for (int q4 = 0; q4 < 2; ++q4) {
            const float4 xv = xp[q4];
            #pragma unroll
            for (int e = 0; e < 4; ++e) {
                const double xd = (e == 0 ? xv.x : e == 1 ? xv.y : e == 2 ? xv.z : xv.w);
                double vv = v[q4 * 4 + e];
                vv = vv + (xd - vv) * 0.5;
                const int s = (vv - 1.0 >= 0.0) ? 1 : 0;
                if (s) vv = 0.0;
                v[q4 * 4 + e] = vv;
                sp[q4 * 4 + e] = s;
            }
        }
        unsigned lo4 = 0u, hi4 = 0u, hp4 = 0u;
        #pragma unroll
        for (int pr = 0; pr < 4; ++pr) {
            const int lo = sp[2 * pr] + sp[2 * pr + 1];
            const int hi = sp[2 * pr] - sp[2 * pr + 1];
            const int sh = 8 * pr;
            lo4 |= (unsigned)(lo & 0xFF) << sh;
            hi4 |= (unsigned)(hi & 0xFF) << sh;
            hp4 |= (unsigned)(hi + 1) << sh;
        }
        *(unsigned*)(h1c + ((size_t)((t * 8 + b) * 512 + c)) * 512 + r * 16 + (pg & 3) * 4) = lo4;
        *(unsigned*)(h1c + ((size_t)((t * 8 + b) * 512 + 256 + c)) * 512 + r * 16 + (pg & 3) * 4) = hi4;
        // histogram: partner row via pg^4
        const unsigned plo = __shfl_xor(lo4, 4, 64);
        const unsigned php = __shfl_xor(hp4, 4, 64);
        if (!(pg & 4)) {
            const unsigned sw = lo4 + plo;
            const unsigned dw = lo4 + (0x02020202u - plo);
            const unsigned uw = hp4 + php;
            const unsigned vw = hp4 + (0x02020202u - php);
            #pragma unroll
            for (int j = 0; j < 4; ++j) {
                const int sh = 8 * j;
                cs  += 1ull << (12 * ((sw >> sh) & 0x7));
                cdd += 1ull << (12 * ((dw >> sh) & 0x7));
                cu  += 1ull << (12 * ((uw >> sh) & 0x7));
                cv  += 1ull << (12 * ((vw >> sh) & 0x7));
            }
        }
        unsigned u[4];
        #pragma unroll
        for (int k = 0; k < 4; ++k)
            u[k] = (sp[2 * k] ? 0x3F80u : 0u) | (sp[2 * k + 1] ? 0x3F800000u : 0u);
        const int base = t * 4096 + d * 256 + pg * 16;
        const int sw2 = (d & 3) << 4;
        *(uint4*)(tr + (base ^ sw2)) = make_uint4(u[0], u[1], u[2], u[3]);
    }
    __syncthreads();
    #pragma unroll
    for (int t = 0; t < T_; ++t) {
        const int p = tid >> 1, half = tid & 1;
        unsigned o[4];
        #pragma unroll
        for (int k = 0; k < 4; ++k) {
            const int dd0 = half * 8 + 2 * k, dd1 = dd0 + 1;
            const char* sl = tr + t * 4096;
            const unsigned short a0 = *(const unsigned short*)(sl + ((dd0 * 256 + p * 2) ^ ((dd0 & 3) << 4)));
            const unsigned short a1 = *(const unsigned short*)(sl + ((dd1 * 256 + p * 2) ^ ((dd1 & 3) << 4)));
            o[k] = (unsigned)a0 | ((unsigned)a1 << 16);
        }
        unsigned short* dst = xsT + (((size_t)((t * 8 + b) * 16 + nb)) * 1024 + qh * 128 + p) * 16 + half * 8;
        *(uint4*)dst = make_uint4(o[0], o[1], o[2], o[3]);
    }
    #pragma unroll
    for (int m = 1; m < 16; m <<= 1) {
        {
            const unsigned a = __shfl_xor((unsigned)cs, m, 64);
            const unsigned bb2 = __shfl_xor((unsigned)(cs >> 32), m, 64);
            cs += ((unsigned long long)bb2 << 32) | a;
        }
        {
            const unsigned a = __shfl_xor((unsigned)cdd, m, 64);
            const unsigned bb2 = __shfl_xor((unsigned)(cdd >> 32), m, 64);
            cdd += ((unsigned long long)bb2 << 32) | a;
        }
        {
            const unsigned a = __shfl_xor((unsigned)cu, m, 64);
            const unsigned bb2 = __shfl_xor((unsigned)(cu >> 32), m, 64);
            cu += ((unsigned long long)bb2 << 32) | a;
        }
        {
            const unsigned a = __shfl_xor((unsigned)cv, m, 64);
            const unsigned bb2 = __shfl_xor((unsigned)(cv >> 32), m, 64);
            cv += ((unsigned long long)bb2 << 32) | a;
        }
    }
    if (pg == 0) {
        // exclusive slot: rep = b*8+qh (64 reps), layout [rep][bin][c] -> plain stores
        int* hh = hist + ((size_t)(b * 8 + qh) * 20) * 256 + c;
        #pragma unroll
        for (int k = 0; k < 5; ++k) {
            hh[k * 256]         = (int)((cs  >> (12 * k)) & 0xFFF);
            hh[(5 + k) * 256]   = (int)((cdd >> (12 * k)) & 0xFFF);
            hh[(10 + k) * 256]  = (int)((cu  >> (12 * k)) & 0xFFF);
            hh[(15 + k) * 256]  = (int)((cv  >> (12 * k)) & 0xFFF);
        }
    }
    if (blockIdx.x == 0) {
        const int lane = tid & 63, grp = tid >> 6;
        if (grp == 0) {
            short8 awc2[5], awc1;
            conv_frags(w1, w2w, lane, awc2, awc1);
            #pragma unroll
            for (int m = 0; m < 5; ++m) *(short8*)&convW[(m * 64 + lane) * 8] = awc2[m];
            *(short8*)&convW[(5 * 64 + lane) * 8] = awc1;
        }
        short8 am[4];
        mix_frags_q(hw, grp, lane, am);
        #pragma unroll
        for (int qq = 0; qq < 4; ++qq) *(short8*)&mixW[((grp * 4 + qq) * 64 + lane) * 8] = am[qq];
    }
}

// ---- exact BN1 + gated BN2 -> 5-entry bf16 LUT ----
__device__ __forceinline__ void lut_prologue(const int* __restrict__ hist, int gb, int tid,
                                             const float* __restrict__ g_fwd, const float* __restrict__ b_fwd,
                                             const float* __restrict__ g_mul, const float* __restrict__ b_mul,
                                             int* histL, double* bn1L, unsigned short* lutL) {
    {
        const int i = tid & 15;
        const int c = gb * 16 + i;
        for (int kk = tid >> 4; kk < 20; kk += 16) {
            int s = 0;
            #pragma unroll
            for (int rep = 0; rep < NHREP; ++rep) s += hist[((size_t)(rep * 20 + kk)) * 256 + c];
            histL[i * 20 + kk] = s;
        }
    }
    __syncthreads();
    if (tid < 32) {
        const int i = tid & 15, hiF = tid >> 4;
        const int* hl = &histL[i * 20 + hiF * 10];
        double sc = 0.0, s2a = 0.0, s2b = 0.0;
        #pragma unroll
        for (int k = 0; k < 5; ++k) {
            const double c0 = (double)hl[k], c1 = (double)hl[5 + k];
            const int cval = hiF ? (k - 2) : k;
            sc += c0 * cval;
            s2a += c0 * (cval * cval);
            s2b += c1 * ((k - 2) * (k - 2));
        }
        const double sum = sc * INVS2_;
        const double sq = (0.5 * (s2a + s2b)) * 0.5;
        const double m = sum / 16384.0, var = sq / 16384.0 - m * m;
        const int gch = hiF * 256 + gb * 16 + i;
        const double a = (double)g_fwd[gch] / sqrt(var + EPS_);
        bn1L[hiF * 32 + i] = a * INVS2_;
        bn1L[hiF * 32 + 16 + i] = (double)b_fwd[gch] - m * a;
    }
    __syncthreads();
    if (tid < 64) {
        const int i = tid & 15, b4 = tid >> 4;
        const int hiF = b4 >> 1;
        const double A1 = bn1L[hiF * 32 + i], B1 = bn1L[hiF * 32 + 16 + i];
        const int* hl = &histL[i * 20 + b4 * 5];
        double gv[5], S = 0.0, Q = 0.0;
        #pragma unroll
        for (int k = 0; k < 5; ++k) {
            const int code = (b4 == 0) ? k : (k - 2);
            double val = ((b4 & 1) == 0) ? ((double)code * A1 + 2.0 * B1) * INVS2_
                                         : ((double)code * A1) * INVS2_;
            val = (fabs(val) - 0.5 >= 0.0) ? val : 0.0;
            gv[k] = val;
            const double cnt = (double)hl[k];
            S += cnt * val; Q += cnt * val * val;
        }
        const double e = Q / 8192.0;
        const double tau = (b4 == 0) ? 0.01 : (b4 == 3 ? 0.05 : 0.02);
        const int gch = b4 * 256 + gb * 16 + i;
        float A2, B2;
        if (e - tau >= 0.0) {
            const double m = S / 8192.0, var = Q / 8192.0 - m * m;
            const double a = (double)g_mul[gch] / sqrt(var + EPS_);
            A2 = (float)a; B2 = (float)((double)b_mul[gch] - m * a);
        } else { A2 = 0.0f; B2 = b_mul[gch]; }
        #pragma unroll
        for (int k = 0; k < 5; ++k)
            lutL[(i * 4 + b4) * 5 + k] = f2bf(fmaf((float)gv[k], A2, B2));
    }
    __syncthreads();
}

// ---- conv MFMA on a staged tile ----
__device__ __forceinline__ void conv_tile(const unsigned short* tile, int lane, int h, int w0,
                                          const short8* awc2, const short8& awc1,
                                          f32x4& acc2o, f32x4& acc1o) {
    const int g = lane >> 4, n = lane & 15, dA = (g & 1) * 8;
    short8 bf[6];
    #pragma unroll
    for (int m = 0; m < 6; ++m) {
        const int t = (m < 4) ? (2 * m + (g >> 1)) : ((m == 4) ? 8 : 4);
        const int ky = t / 3, kx = t % 3;
        const int rr = h + ky, cc = w0 + n + kx;
        const int addr = (((rr * 34 + cc) * 32) + dA * 2) ^ ((cc & 4) << 2);
        bf[m] = *(const short8*)((const char*)tile + addr);
    }
    f32x4 acc2 = {0.f, 0.f, 0.f, 0.f};
    #pragma unroll
    for (int m = 0; m < 5; ++m)
        acc2 = __builtin_amdgcn_mfma_f32_16x16x32_bf16(awc2[m], bf[m], acc2, 0, 0, 0);
    const f32x4 z = {0.f, 0.f, 0.f, 0.f};
    acc1o = __builtin_amdgcn_mfma_f32_16x16x32_bf16(awc1, bf[5], z, 0, 0, 0);
    acc2o = acc2;
}

__device__ __forceinline__ void stage_rows(const unsigned short* __restrict__ src,
                                           int r0, int nr, int tid, unsigned short* tile) {
    const int total = nr * 34;
    for (int idx = tid; idx < total; idx += 256) {
        const int r = r0 + idx / 34, cpos = idx % 34;
        const int gh = r - 1, gw = cpos - 1;
        uint4 v0 = make_uint4(0u, 0u, 0u, 0u), v1 = v0;
        if (((unsigned)gh < 32u) & ((unsigned)gw < 32u)) {
            const char* sp = (const char*)(src + (size_t)(gh * 32 + gw) * 16);
            v0 = *(const uint4*)sp;
            v1 = *(const uint4*)(sp + 16);
        }
        const int base = ((r - r0) * 34 + cpos) * 32;
        const int sw = (cpos & 4) << 2;
        *(uint4*)((char*)tile + (base ^ sw)) = v0;
        *(uint4*)((char*)tile + ((base + 16) ^ sw)) = v1;
    }
}

// ============ KMID: [0,2048) mix (LUT coef + MFMA + S3 + coef dump); [2048,4096) conv stats ============
__global__ __launch_bounds__(256) void kmid(const signed char* __restrict__ h1c,
                                            const unsigned short* __restrict__ xsT,
                                            double* __restrict__ st,
                                            char* __restrict__ coefD,
                                            const int* __restrict__ hist,
                                            const unsigned short* __restrict__ mixW,
                                            const unsigned short* __restrict__ convW,
                                            const float* __restrict__ g_fwd, const float* __restrict__ b_fwd,
                                            const float* __restrict__ g_mul, const float* __restrict__ b_mul) {
    __shared__ __align__(16) char smem[15232];
    const int tid = threadIdx.x, lane = tid & 63, wid = tid >> 6;
    if (blockIdx.x < 2048) {
        float* pad = (float*)smem;                              // 512
        unsigned short* lutL = (unsigned short*)(smem + 512);   // 640
        int* histL = (int*)(smem + 1152);                       // 1280
        double* bn1L = (double*)(smem + 2432);                  // 512
        signed char* rawL = (signed char*)(smem + 2944);        // 4096
        unsigned short* coefL = (unsigned short*)(smem + 7040); // 8192
        const int pb = blockIdx.x & 3, gb = (blockIdx.x >> 2) & 15, tb = blockIdx.x >> 6;
        {
            const int ch = tid >> 3, o8 = (tid & 7) * 16;
            const int cab = (ch < 16) ? gb * 16 + ch : 256 + gb * 16 + (ch - 16);
            *(uint4*)(rawL + ch * 128 + o8) =
                *(const uint4*)(h1c + ((size_t)(tb * 512 + cab)) * 512 + pb * 128 + o8);
        }
        lut_prologue(hist, gb, tid, g_fwd, b_fwd, g_mul, b_mul, histL, bn1L, lutL);
        {
            const int p = tid & 63, ds = tid >> 6;
            const int h2l = p >> 4, w2 = p & 15;
            unsigned pk[4][2];
            #pragma unroll
            for (int dd = 0; dd < 4; ++dd) {
                const int d = ds * 4 + dd;
                const int base = d * 128 + (2 * h2l) * 16 + w2;
                const int l0 = rawL[base], l1 = rawL[base + 16];
                const int q0 = rawL[2048 + base], q1 = rawL[2048 + base + 16];
                const unsigned short* lp = &lutL[d * 20];
                const unsigned hv[4] = { lp[l0 + l1],
                                         lp[5 + l0 - l1 + 2],
                                         lp[10 + q0 + q1 + 2],
                                         lp[15 + q0 - q1 + 2] };
                #pragma unroll
                for (int q = 0; q < 4; ++q) {
                    if (dd & 1) pk[q][dd >> 1] |= hv[q] << 16;
                    else        pk[q][dd >> 1] = hv[q];
                }
            }
            #pragma unroll
            for (int q = 0; q < 4; ++q) {
                const int slot = (((q & 1) * 2 + (ds >> 1)) ^ (p & 3));
                char* dst = (char*)coefL + (q >> 1) * 4096 + p * 64 + slot * 16 + (ds & 1) * 8;
                *(uint2*)dst = make_uint2(pk[q][0], pk[q][1]);
            }
        }
        short8 am[4];
        load_mix_frags(mixW, gb >> 2, lane, am);
        __syncthreads();
        {   // dump coefL slice to global (8 KB)
            char* base = coefD + ((size_t)(tb * 16 + gb)) * 32768 + pb * 4096;
            const int i = tid * 32;
            const int pair = i >> 12, loc = i & 4095;
            *(uint4*)(base + pair * 16384 + loc) = *(const uint4*)((const char*)coefL + i);
            *(uint4*)(base + pair * 16384 + loc + 16) = *(const uint4*)((const char*)coefL + i + 16);
        }
        const int o = lane & 15, g = lane >> 4;
        const int Pl = wid * 16 + o;
        f32x4 Mh[4];
        #pragma unroll
        for (int p = 0; p < 2; ++p) {
            const int slot = g ^ (o & 3);
            const short8 bf = *(const short8*)((const char*)coefL + p * 4096 + Pl * 64 + slot * 16);
            const f32x4 z = {0.f, 0.f, 0.f, 0.f};
            Mh[2 * p]     = __builtin_amdgcn_mfma_f32_16x16x32_bf16(am[2 * p], bf, z, 0, 0, 0);
            Mh[2 * p + 1] = __builtin_amdgcn_mfma_f32_16x16x32_bf16(am[2 * p + 1], bf, z, 0, 0, 0);
        }
        float s2x[4], se[4];
        #pragma unroll
        for (int r = 0; r < 4; ++r) {
            s2x[r] = 2.0f * Mh[0][r];
            se[r] = Mh[0][r] * Mh[0][r] + Mh[1][r] * Mh[1][r] + Mh[2][r] * Mh[2][r] + Mh[3][r] * Mh[3][r];
        }
        #pragma unroll
        for (int r = 0; r < 4; ++r)
            #pragma unroll
            for (int m = 1; m < 16; m <<= 1) {
                s2x[r] += __shfl_xor(s2x[r], m, 64);
                se[r]  += __shfl_xor(se[r], m, 64);
            }
        if ((lane & 15) == 0) {
            #pragma unroll
            for (int r = 0; r < 4; ++r) {
                pad[(wid * 16 + g * 4 + r) * 2]     = s2x[r];
                pad[(wid * 16 + g * 4 + r) * 2 + 1] = se[r];
            }
        }
        __syncthreads();
        if (tid < 32) {
            const int j = tid >> 1, s = tid & 1;
            const float tot = pad[(0 * 16 + j) * 2 + s] + pad[(1 * 16 + j) * 2 + s]
                            + pad[(2 * 16 + j) * 2 + s] + pad[(3 * 16 + j) * 2 + s];
            double* stw = st + (((((tb & 3) << 2) | pb)) * NST);
            atomicAdd(&stw[(s ? S3Q : S3S) + gb * 16 + j], (double)tot);
        }
    } else {
        const int bid = blockIdx.x - 2048;
        const int hb = bid & 3, gb = (bid >> 2) & 15, tb = bid >> 6;
        unsigned short* tile = (unsigned short*)smem;           // 10880
        float* pad = (float*)(smem + 10880);                    // 1024
        const unsigned short* src = xsT + (size_t)(tb * 16 + gb) * 1024 * 16;
        stage_rows(src, hb * 8, 10, tid, tile);
        short8 awc2[5], awc1;
        load_conv_frags(convW, lane, awc2, awc1);
        __syncthreads();
        float t1s[4] = {0, 0, 0, 0}, t1q[4] = {0, 0, 0, 0};
        float t2s[4] = {0, 0, 0, 0}, t2q[4] = {0, 0, 0, 0};
        #pragma unroll
        for (int ti = 0; ti < 4; ++ti) {
            const int lr = wid * 2 + (ti >> 1);
            const int w0 = (ti & 1) * 16;
            f32x4 a2v, a1v;
            conv_tile(tile, lane, lr, w0, awc2, awc1, a2v, a1v);
            #pragma unroll
            for (int r = 0; r < 4; ++r) {
                t1s[r] += a1v[r]; t1q[r] += a1v[r] * a1v[r];
                t2s[r] += a2v[r]; t2q[r] += a2v[r] * a2v[r];
            }
        }
        #pragma unroll
        for (int r = 0; r < 4; ++r)
            #pragma unroll
            for (int m = 1; m < 16; m <<= 1) {
                t1s[r] += __shfl_xor(t1s[r], m, 64);
                t1q[r] += __shfl_xor(t1q[r], m, 64);
                t2s[r] += __shfl_xor(t2s[r], m, 64);
                t2q[r] += __shfl_xor(t2q[r], m, 64);
            }
        if ((lane & 15) == 0) {
            const int G = lane >> 4;
            #pragma unroll
            for (int r = 0; r < 4; ++r) {
                const int oc = G * 4 + r;
                pad[(wid * 16 + oc) * 4 + 0] = t1s[r];
                pad[(wid * 16 + oc) * 4 + 1] = t1q[r];
                pad[(wid * 16 + oc) * 4 + 2] = t2s[r];
                pad[(wid * 16 + oc) * 4 + 3] = t2q[r];
            }
        }
        __syncthreads();
        if (tid < 64) {
            const int oc = tid >> 2, arr = tid & 3;
            const float vv = pad[(0 * 16 + oc) * 4 + arr] + pad[(1 * 16 + oc) * 4 + arr]
                           + pad[(2 * 16 + oc) * 4 + arr] + pad[(3 * 16 + oc) * 4 + arr];
            const int ch = gb * 16 + oc;
            const int off = (arr == 0 ? S4S : arr == 1 ? S4Q : arr == 2 ? S5S : S5Q) + ch;
            double* stw = st + (((((tb & 3) << 2) | hb)) * NST);
            atomicAdd(&stw[off], (double)vv);
        }
    }
}

// ============ KFIN: 1024 blocks (tb, gb, half) — 18-row tile + 8-h2-row coef slice ============
__global__ __launch_bounds__(256) void kfin(const unsigned short* __restrict__ xsT,
                                            const char* __restrict__ coefD,
                                            const double* __restrict__ st,
                                            const unsigned short* __restrict__ convW,
                                            const unsigned short* __restrict__ mixW,
                                            const float* __restrict__ g_inv, const float* __restrict__ b_inv,
                                            const float* __restrict__ g_c1, const float* __restrict__ b_c1,
                                            const float* __restrict__ g_c2, const float* __restrict__ b_c2,
                                            const float* __restrict__ conv1_b, const float* __restrict__ conv2_b,
                                            float* __restrict__ out) {
    __shared__ __align__(16) char smem[36224];
    const int tid = threadIdx.x, lane = tid & 63, wid = tid >> 6;
    const int hf = blockIdx.x & 1, gb = (blockIdx.x >> 1) & 15, tb = blockIdx.x >> 5;
    unsigned short* tile  = (unsigned short*)smem;            // 19584
    unsigned short* coefL = (unsigned short*)(smem + 19584);  // 16384
    float* PA3 = (float*)(smem + 35968);
    float* PA4 = PA3 + 16; float* PA5 = PA3 + 32; float* PK = PA3 + 48;
    if (tid < 16) {
        const int oc = tid, c = gb * 16 + oc;
        const double n3 = 32768.0;
        const double s3 = st_sum(st, S3S + c), q3 = st_sum(st, S3Q + c);
        const double m3 = s3 / n3, var3 = q3 / n3 - m3 * m3;
        const double a3 = (double)g_inv[c] / sqrt(var3 + EPS_);
        const double bias1 = (double)conv1_b[oc];
        const double s4r = st_sum(st, S4S + c), q4r = st_sum(st, S4Q + c);
        const double s4 = s4r + n3 * bias1;
        const double q4v = q4r + 2.0 * bias1 * s4r + n3 * bias1 * bias1;
        const double m4 = s4 / n3, var4 = q4v / n3 - m4 * m4;
        const double a4 = (double)g_c1[c] / sqrt(var4 + EPS_);
        const double bias2 = (double)conv2_b[oc];
        const double s5r = st_sum(st, S5S + c), q5r = st_sum(st, S5Q + c);
        const double s5 = s5r + n3 * bias2;
        const double q5v = q5r + 2.0 * bias2 * s5r + n3 * bias2 * bias2;
        const double m5 = s5 / n3, var5 = q5v / n3 - m5 * m5;
        const double a5 = (double)g_c2[c] / sqrt(var5 + EPS_);
        PA3[oc] = (float)a3; PA4[oc] = (float)a4; PA5[oc] = (float)a5;
        PK[oc] = (float)(((double)b_inv[c] - m3 * a3) + ((double)b_c1[c] - m4 * a4)
                       + ((double)b_c2[c] - m5 * a5) + a4 * bias1 + a5 * bias2);
    }
    stage_rows(xsT + (size_t)(tb * 16 + gb) * 1024 * 16, hf * 16, 18, tid, tile);
    {
        const char* dump = coefD + ((size_t)(tb * 16 + gb)) * 32768 + hf * 8192;
        #pragma unroll
        for (int i = 0; i < 4; ++i)
            *(uint4*)((char*)coefL + i * 4096 + tid * 16) =
                *(const uint4*)(dump + (i >> 1) * 16384 + (i & 1) * 4096 + tid * 16);
    }
    short8 am[4], awc2[5], awc1;
    load_mix_frags(mixW, gb >> 2, lane, am);
    load_conv_frags(convW, lane, awc2, awc1);
    __syncthreads();
    const int G = lane >> 4, n = lane & 15;
    float fA3[4], fA4[4], fA5[4], fK[4];
    #pragma unroll
    for (int r = 0; r < 4; ++r) {
        const int oc = G * 4 + r;
        fA3[r] = PA3[oc]; fA4[r] = PA4[oc]; fA5[r] = PA5[oc]; fK[r] = PK[oc];
    }
    const float sw = (n & 1) ? -1.0f : 1.0f;
    #pragma unroll
    for (int hh2 = 0; hh2 < 2; ++hh2) {
        f32x4 Mh[4];
        {
            const int o = lane & 15, g = lane >> 4;
            const int Pl = (wid * 2 + hh2) * 16 + o;
            #pragma unroll
            for (int p = 0; p < 2; ++p) {
                const int slot = g ^ (o & 3);
                const short8 bf = *(const short8*)((const char*)coefL + p * 8192 + Pl * 64 + slot * 16);
                const f32x4 z = {0.f, 0.f, 0.f, 0.f};
                Mh[2 * p]     = __builtin_amdgcn_mfma_f32_16x16x32_bf16(am[2 * p], bf, z, 0, 0, 0);
                Mh[2 * p + 1] = __builtin_amdgcn_mfma_f32_16x16x32_bf16(am[2 * p + 1], bf, z, 0, 0, 0);
            }
        }
        #pragma unroll
        for (int w0h = 0; w0h < 2; ++w0h) {
            const int src = (lane & 48) + w0h * 8 + (n >> 1);
            float ms[4][4];
            #pragma unroll
            for (int q = 0; q < 4; ++q)
                #pragma unroll
                for (int r = 0; r < 4; ++r) ms[q][r] = __shfl(Mh[q][r], src, 64);
            #pragma unroll
            for (int hrow = 0; hrow < 2; ++hrow) {
                const float sh = hrow ? -1.0f : 1.0f;
                const int hl = wid * 4 + hh2 * 2 + hrow;
                const int hglob = hf * 16 + hl;
                const int w0 = w0h * 16;
                f32x4 a2v, a1v;
                conv_tile(tile, lane, hl, w0, awc2, awc1, a2v, a1v);
                #pragma unroll
                for (int r = 0; r < 4; ++r) {
                    const float rec = 0.5f * ((ms[0][r] + sh * ms[1][r]) + sw * (ms[2][r] + sh * ms[3][r]));
                    const int oc = G * 4 + r;
                    const size_t ai = ((size_t)(tb * 256 + gb * 16 + oc)) * 1024 + (size_t)hglob * 32 + w0 + n;
                    out[ai] = fA3[r] * rec + fA4[r] * a1v[r] + fA5[r] * a2v[r] + fK[r];
                }
            }
        }
    }
}

extern "C" void kernel_launch(void* const* d_in, const int* in_sizes, int n_in,
                              void* d_out, int out_size, void* d_ws, size_t ws_size,
                              hipStream_t stream) {
    const float* x        = (const float*)d_in[0];
    const float* haar_w   = (const float*)d_in[1];
    const float* conv1_w  = (const float*)d_in[2];
    const float* conv1_b  = (const float*)d_in[3];
    const float* conv2_w  = (const float*)d_in[4];
    const float* conv2_b  = (const float*)d_in[5];
    const float* g_fwd    = (const float*)d_in[6];
    const float* b_fwd    = (const float*)d_in[7];
    const float* g_mul    = (const float*)d_in[8];
    const float* b_mul    = (const float*)d_in[9];
    const float* g_inv    = (const float*)d_in[10];
    const float* b_inv    = (const float*)d_in[11];
    const float* g_c1     = (const float*)d_in[12];
    const float* b_c1     = (const float*)d_in[13];
    const float* g_c2     = (const float*)d_in[14];
    const float* b_c2     = (const float*)d_in[15];
    float* out = (float*)d_out;

    char* ws = (char*)d_ws;
    unsigned short* xsT = (unsigned short*)(ws + XST_OFF);
    signed char* h1c    = (signed char*)(ws + H1C_OFF);
    char* coefD         = ws + COEF_OFF;
    double* st          = (double*)(ws + ST_OFF);
    unsigned short* convW = (unsigned short*)(ws + WTAB_OFF);
    unsigned short* mixW  = (unsigned short*)(ws + WTAB_OFF + 6144);
    int* hist           = (int*)(ws + HIST_OFF);

    k1_lif<<<dim3(1024), dim3(256), 0, stream>>>(x, xsT, h1c, hist, st,
                                                 conv1_w, conv2_w, haar_w, convW, mixW);
    kmid<<<dim3(4096), dim3(256), 0, stream>>>(h1c, xsT, st, coefD, hist, mixW, convW,
                                               g_fwd, b_fwd, g_mul, b_mul);
    kfin<<<dim3(1024), dim3(256), 0, stream>>>(xsT, coefD, st, convW, mixW,
                                               g_inv, b_inv, g_c1, b_c1, g_c2, b_c2,
                                               conv1_b, conv2_b, out);
}

// Round 15
// 63.253 us; speedup vs baseline: 1.4782x; 1.4782x over previous
//
#include <hip/hip_runtime.h>

#define T_ 4
#define B_ 8
#define C_ 256
#define TB_ 32
#define SQRT2_ 1.4142135623730951
#define INVS2_ 0.7071067811865475
#define EPS_ 1e-5

typedef __attribute__((ext_vector_type(8))) short short8;
typedef __attribute__((ext_vector_type(4))) float f32x4;

// ---- workspace layout ----
#define XST_OFF  ((size_t)0)           // bf16 xsT [tb][nb][pos1024][d16]  16 MB
#define H1C_OFF  ((size_t)16777216)    // i8 h1 codes                       8 MB
#define COEF_OFF ((size_t)25165824)    // bf16 coef dumps                  16 MB
#define ST_OFF   ((size_t)41943040)    // doubles stats, 16 reps x 4608 (S3..S5 used)
#define WTAB_OFF ((size_t)42532864)    // convW 6KB + mixW 16KB
#define HIST_OFF ((size_t)42555392)    // int hist[32rep][20bin][256c]  640KB
#define LUTG_OFF ((size_t)43210752)    // bf16 lutG[16gb][320]  10KB
#define S3S 3072
#define S3Q 3328
#define S4S 3584
#define S4Q 3840
#define S5S 4096
#define S5Q 4352
#define NST 4608
#define NREP 16
#define NHREP 32

__device__ __forceinline__ unsigned short f2bf(float v) {
    union { float f; unsigned u; } x; x.f = v;
    unsigned r = x.u + 0x7FFFu + ((x.u >> 16) & 1u);
    return (unsigned short)(r >> 16);
}

__device__ __forceinline__ double st_sum(const double* __restrict__ st, int idx) {
    double s = 0.0;
    #pragma unroll
    for (int r = 0; r < NREP; ++r) s += st[r * NST + idx];
    return s;
}

// ---- fragment builders (k1 block 0 only) ----
__device__ __forceinline__ void mix_frags_q(const float* __restrict__ hw, int gbq, int lane, short8 am[4]) {
    const int o = lane & 15, g = lane >> 4;
    #pragma unroll
    for (int q = 0; q < 4; ++q) {
        #pragma unroll
        for (int e = 0; e < 8; ++e) {
            const int kk = g * 8 + e;
            unsigned short v = 0;
            if ((kk >> 4) == (q & 1)) {
                const int d = kk & 15;
                const int nbp = q * 4 + gbq;
                v = f2bf(hw[(nbp * 16 + d) * 16 + o]);
            }
            am[q][e] = (short)v;
        }
    }
}

__device__ __forceinline__ void conv_frags(const float* __restrict__ w1, const float* __restrict__ w2w,
                                           int lane, short8* awc2, short8& awc1) {
    const int o = lane & 15, g = lane >> 4, dA = (g & 1) * 8;
    #pragma unroll
    for (int m = 0; m < 5; ++m) {
        const int t = (m < 4) ? (2 * m + (g >> 1)) : 8;
        const bool act = (m < 4) || (g < 2);
        #pragma unroll
        for (int j = 0; j < 8; ++j) {
            const float wv = act ? w2w[(o * 16 + dA + j) * 9 + t] : 0.0f;
            awc2[m][j] = (short)f2bf(wv);
        }
    }
    #pragma unroll
    for (int j = 0; j < 8; ++j) {
        const float wv = (g < 2) ? w1[o * 16 + dA + j] : 0.0f;
        awc1[j] = (short)f2bf(wv);
    }
}

__device__ __forceinline__ void load_conv_frags(const unsigned short* __restrict__ convW,
                                                int lane, short8* awc2, short8& awc1) {
    #pragma unroll
    for (int m = 0; m < 5; ++m) awc2[m] = *(const short8*)&convW[(m * 64 + lane) * 8];
    awc1 = *(const short8*)&convW[(5 * 64 + lane) * 8];
}
__device__ __forceinline__ void load_mix_frags(const unsigned short* __restrict__ mixW,
                                               int gbq, int lane, short8 am[4]) {
    #pragma unroll
    for (int q = 0; q < 4; ++q) am[q] = *(const short8*)&mixW[((gbq * 4 + q) * 64 + lane) * 8];
}

// ============ K1: LIF (fp64) -> xsT, h1c, exclusive-slot histograms; zero st; block0 builds tables ============
__global__ __launch_bounds__(256) void k1_lif(const float* __restrict__ x,
                                              unsigned short* __restrict__ xsT,
                                              signed char* __restrict__ h1c,
                                              int* __restrict__ hist,
                                              double* __restrict__ st,
                                              const float* __restrict__ w1, const float* __restrict__ w2w,
                                              const float* __restrict__ hw,
                                              unsigned short* __restrict__ convW,
                                              unsigned short* __restrict__ mixW) {
    const int q = blockIdx.x & 3, nb = (blockIdx.x >> 2) & 15, b = blockIdx.x >> 6;
    const int tid = threadIdx.x;
    if (tid < 72) {
        double2 z2; z2.x = 0.0; z2.y = 0.0;
        *(double2*)(st + (size_t)blockIdx.x * 144 + tid * 2) = z2;
    }
    const int d = tid >> 4, pg = tid & 15;
    const int c = nb * 16 + d;
    const int h = q * 8 + (pg >> 1), wseg = (pg & 1) * 16;
    __shared__ __align__(16) char tr[32768];   // 4 t-slices x 8192
    double v[16];
    #pragma unroll
    for (int i = 0; i < 16; ++i) v[i] = 0.0;
    unsigned long long cs = 0, cdd = 0, cu = 0, cv = 0;
    #pragma unroll
    for (int t = 0; t < T_; ++t) {
        const size_t xi = ((size_t)((t * 8 + b) * 256 + c)) * 1024 + h * 32 + wseg;
        const float4* xp = (const float4*)(x + xi);
        int sp[16];
        #pragma unroll
        for (int q4 = 0; q4 < 4; ++q4) {
            const float4 xv = xp[q4];
            #pragma unroll
            for (int e = 0; e < 4; ++e) {
                const double xd = (e == 0 ? xv.x : e == 1 ? xv.y : e == 2 ? xv.z : xv.w);
                double vv = v[q4 * 4 + e];
                vv = vv + (xd - vv) * 0.5;
                const int s = (vv - 1.0 >= 0.0) ? 1 : 0;
                if (s) vv = 0.0;
                v[q4 * 4 + e] = vv;
                sp[q4 * 4 + e] = s;
            }
        }
        unsigned lo8[2] = {0u, 0u}, hi8[2] = {0u, 0u}, hp8[2] = {0u, 0u};
        #pragma unroll
        for (int pr = 0; pr < 8; ++pr) {
            const int lo = sp[2 * pr] + sp[2 * pr + 1];
            const int hi = sp[2 * pr] - sp[2 * pr + 1];
            const int sh = 8 * (pr & 3);
            lo8[pr >> 2] |= (unsigned)(lo & 0xFF) << sh;
            hi8[pr >> 2] |= (unsigned)(hi & 0xFF) << sh;
            hp8[pr >> 2] |= (unsigned)(hi + 1) << sh;
        }
        const size_t lob = ((size_t)((t * 8 + b) * 512 + c)) * 512 + h * 16 + (pg & 1) * 8;
        const size_t hib = ((size_t)((t * 8 + b) * 512 + 256 + c)) * 512 + h * 16 + (pg & 1) * 8;
        *(uint2*)(h1c + lob) = make_uint2(lo8[0], lo8[1]);
        *(uint2*)(h1c + hib) = make_uint2(hi8[0], hi8[1]);
        const unsigned plo0 = __shfl_xor(lo8[0], 2, 64);
        const unsigned plo1 = __shfl_xor(lo8[1], 2, 64);
        const unsigned php0 = __shfl_xor(hp8[0], 2, 64);
        const unsigned php1 = __shfl_xor(hp8[1], 2, 64);
        if (!(pg & 2)) {
            const unsigned sw0 = lo8[0] + plo0, sw1 = lo8[1] + plo1;
            const unsigned dw0 = lo8[0] + (0x02020202u - plo0), dw1 = lo8[1] + (0x02020202u - plo1);
            const unsigned uw0 = hp8[0] + php0, uw1 = hp8[1] + php1;
            const unsigned vw0 = hp8[0] + (0x02020202u - php0), vw1 = hp8[1] + (0x02020202u - php1);
            #pragma unroll
            for (int j = 0; j < 4; ++j) {
                const int sh = 8 * j;
                cs  += 1ull << (12 * ((sw0 >> sh) & 0x7));
                cs  += 1ull << (12 * ((sw1 >> sh) & 0x7));
                cdd += 1ull << (12 * ((dw0 >> sh) & 0x7));
                cdd += 1ull << (12 * ((dw1 >> sh) & 0x7));
                cu  += 1ull << (12 * ((uw0 >> sh) & 0x7));
                cu  += 1ull << (12 * ((uw1 >> sh) & 0x7));
                cv  += 1ull << (12 * ((vw0 >> sh) & 0x7));
                cv  += 1ull << (12 * ((vw1 >> sh) & 0x7));
            }
        }
        unsigned u[8];
        #pragma unroll
        for (int k = 0; k < 8; ++k)
            u[k] = (sp[2 * k] ? 0x3F80u : 0u) | (sp[2 * k + 1] ? 0x3F800000u : 0u);
        const int base = t * 8192 + d * 512 + pg * 32;
        const int sw = (d & 3) << 4;
        *(uint4*)(tr + ((base) ^ sw))      = make_uint4(u[0], u[1], u[2], u[3]);
        *(uint4*)(tr + ((base + 16) ^ sw)) = make_uint4(u[4], u[5], u[6], u[7]);
    }
    __syncthreads();
    #pragma unroll
    for (int t = 0; t < T_; ++t) {
        const int p = tid;
        unsigned o[8];
        #pragma unroll
        for (int dd = 0; dd < 8; ++dd) {
            const char* sl = tr + t * 8192;
            const unsigned short a0 = *(const unsigned short*)(sl + (2 * dd) * 512 + (((p << 1)) ^ (((2 * dd) & 3) << 4)));
            const unsigned short a1 = *(const unsigned short*)(sl + (2 * dd + 1) * 512 + (((p << 1)) ^ (((2 * dd + 1) & 3) << 4)));
            o[dd] = (unsigned)a0 | ((unsigned)a1 << 16);
        }
        unsigned short* dst = xsT + (((size_t)((t * 8 + b) * 16 + nb)) * 1024 + q * 256 + p) * 16;
        *(uint4*)dst = make_uint4(o[0], o[1], o[2], o[3]);
        *(uint4*)(dst + 8) = make_uint4(o[4], o[5], o[6], o[7]);
    }
    #pragma unroll
    for (int m = 1; m < 16; m <<= 1) {
        {
            const unsigned a = __shfl_xor((unsigned)cs, m, 64);
            const unsigned bb2 = __shfl_xor((unsigned)(cs >> 32), m, 64);
            cs += ((unsigned long long)bb2 << 32) | a;
        }
        {
            const unsigned a = __shfl_xor((unsigned)cdd, m, 64);
            const unsigned bb2 = __shfl_xor((unsigned)(cdd >> 32), m, 64);
            cdd += ((unsigned long long)bb2 << 32) | a;
        }
        {
            const unsigned a = __shfl_xor((unsigned)cu, m, 64);
            const unsigned bb2 = __shfl_xor((unsigned)(cu >> 32), m, 64);
            cu += ((unsigned long long)bb2 << 32) | a;
        }
        {
            const unsigned a = __shfl_xor((unsigned)cv, m, 64);
            const unsigned bb2 = __shfl_xor((unsigned)(cv >> 32), m, 64);
            cv += ((unsigned long long)bb2 << 32) | a;
        }
    }
    if (pg == 0) {
        int* hh = hist + ((size_t)(b * 4 + q) * 20) * 256 + c;
        #pragma unroll
        for (int k = 0; k < 5; ++k) {
            hh[k * 256]         = (int)((cs  >> (12 * k)) & 0xFFF);
            hh[(5 + k) * 256]   = (int)((cdd >> (12 * k)) & 0xFFF);
            hh[(10 + k) * 256]  = (int)((cu  >> (12 * k)) & 0xFFF);
            hh[(15 + k) * 256]  = (int)((cv  >> (12 * k)) & 0xFFF);
        }
    }
    if (blockIdx.x == 0) {
        const int lane = tid & 63, grp = tid >> 6;
        if (grp == 0) {
            short8 awc2[5], awc1;
            conv_frags(w1, w2w, lane, awc2, awc1);
            #pragma unroll
            for (int m = 0; m < 5; ++m) *(short8*)&convW[(m * 64 + lane) * 8] = awc2[m];
            *(short8*)&convW[(5 * 64 + lane) * 8] = awc1;
        }
        short8 am[4];
        mix_frags_q(hw, grp, lane, am);
        #pragma unroll
        for (int qq = 0; qq < 4; ++qq) *(short8*)&mixW[((grp * 4 + qq) * 64 + lane) * 8] = am[qq];
    }
}

// ---- exact BN1 + gated BN2 -> 5-entry bf16 LUT (klut only) ----
__device__ __forceinline__ void lut_prologue(const int* __restrict__ hist, int gb, int tid,
                                             const float* __restrict__ g_fwd, const float* __restrict__ b_fwd,
                                             const float* __restrict__ g_mul, const float* __restrict__ b_mul,
                                             int* histL, double* bn1L, unsigned short* lutL) {
    {
        const int i = tid & 15;
        const int c = gb * 16 + i;
        for (int kk = tid >> 4; kk < 20; kk += 16) {
            int s = 0;
            #pragma unroll
            for (int rep = 0; rep < NHREP; ++rep) s += hist[((size_t)(rep * 20 + kk)) * 256 + c];
            histL[i * 20 + kk] = s;
        }
    }
    __syncthreads();
    if (tid < 32) {
        const int i = tid & 15, hiF = tid >> 4;
        const int* hl = &histL[i * 20 + hiF * 10];
        double sc = 0.0, s2a = 0.0, s2b = 0.0;
        #pragma unroll
        for (int k = 0; k < 5; ++k) {
            const double c0 = (double)hl[k], c1 = (double)hl[5 + k];
            const int cval = hiF ? (k - 2) : k;
            sc += c0 * cval;
            s2a += c0 * (cval * cval);
            s2b += c1 * ((k - 2) * (k - 2));
        }
        const double sum = sc * INVS2_;
        const double sq = (0.5 * (s2a + s2b)) * 0.5;
        const double m = sum / 16384.0, var = sq / 16384.0 - m * m;
        const int gch = hiF * 256 + gb * 16 + i;
        const double a = (double)g_fwd[gch] / sqrt(var + EPS_);
        bn1L[hiF * 32 + i] = a * INVS2_;
        bn1L[hiF * 32 + 16 + i] = (double)b_fwd[gch] - m * a;
    }
    __syncthreads();
    if (tid < 64) {
        const int i = tid & 15, b4 = tid >> 4;
        const int hiF = b4 >> 1;
        const double A1 = bn1L[hiF * 32 + i], B1 = bn1L[hiF * 32 + 16 + i];
        const int* hl = &histL[i * 20 + b4 * 5];
        double gv[5], S = 0.0, Q = 0.0;
        #pragma unroll
        for (int k = 0; k < 5; ++k) {
            const int code = (b4 == 0) ? k : (k - 2);
            double val = ((b4 & 1) == 0) ? ((double)code * A1 + 2.0 * B1) * INVS2_
                                         : ((double)code * A1) * INVS2_;
            val = (fabs(val) - 0.5 >= 0.0) ? val : 0.0;
            gv[k] = val;
            const double cnt = (double)hl[k];
            S += cnt * val; Q += cnt * val * val;
        }
        const double e = Q / 8192.0;
        const double tau = (b4 == 0) ? 0.01 : (b4 == 3 ? 0.05 : 0.02);
        const int gch = b4 * 256 + gb * 16 + i;
        float A2, B2;
        if (e - tau >= 0.0) {
            const double m = S / 8192.0, var = Q / 8192.0 - m * m;
            const double a = (double)g_mul[gch] / sqrt(var + EPS_);
            A2 = (float)a; B2 = (float)((double)b_mul[gch] - m * a);
        } else { A2 = 0.0f; B2 = b_mul[gch]; }
        #pragma unroll
        for (int k = 0; k < 5; ++k)
            lutL[(i * 4 + b4) * 5 + k] = f2bf(fmaf((float)gv[k], A2, B2));
    }
    __syncthreads();
}

// ============ KLUT: build per-channel coef LUT once (16 blocks, one per gb) ============
__global__ __launch_bounds__(256) void klut(const int* __restrict__ hist,
                                            const float* __restrict__ g_fwd, const float* __restrict__ b_fwd,
                                            const float* __restrict__ g_mul, const float* __restrict__ b_mul,
                                            unsigned short* __restrict__ lutG) {
    __shared__ __align__(16) char smem[2432];
    int* histL = (int*)smem;                       // 1280
    double* bn1L = (double*)(smem + 1280);         // 512
    unsigned short* lutL = (unsigned short*)(smem + 1792);  // 640
    const int tid = threadIdx.x, gb = blockIdx.x;
    lut_prologue(hist, gb, tid, g_fwd, b_fwd, g_mul, b_mul, histL, bn1L, lutL);
    if (tid < 40)
        *(uint4*)((char*)lutG + gb * 640 + tid * 16) = *(const uint4*)((const char*)lutL + tid * 16);
}

// ---- conv MFMA on a staged tile ----
__device__ __forceinline__ void conv_tile(const unsigned short* tile, int lane, int h, int w0,
                                          const short8* awc2, const short8& awc1,
                                          f32x4& acc2o, f32x4& acc1o) {
    const int g = lane >> 4, n = lane & 15, dA = (g & 1) * 8;
    short8 bf[6];
    #pragma unroll
    for (int m = 0; m < 6; ++m) {
        const int t = (m < 4) ? (2 * m + (g >> 1)) : ((m == 4) ? 8 : 4);
        const int ky = t / 3, kx = t % 3;
        const int rr = h + ky, cc = w0 + n + kx;
        const int addr = (((rr * 34 + cc) * 32) + dA * 2) ^ ((cc & 4) << 2);
        bf[m] = *(const short8*)((const char*)tile + addr);
    }
    f32x4 acc2 = {0.f, 0.f, 0.f, 0.f};
    #pragma unroll
    for (int m = 0; m < 5; ++m)
        acc2 = __builtin_amdgcn_mfma_f32_16x16x32_bf16(awc2[m], bf[m], acc2, 0, 0, 0);
    const f32x4 z = {0.f, 0.f, 0.f, 0.f};
    acc1o = __builtin_amdgcn_mfma_f32_16x16x32_bf16(awc1, bf[5], z, 0, 0, 0);
    acc2o = acc2;
}

__device__ __forceinline__ void stage_rows(const unsigned short* __restrict__ src,
                                           int r0, int nr, int tid, unsigned short* tile) {
    const int total = nr * 34;
    for (int idx = tid; idx < total; idx += 256) {
        const int r = r0 + idx / 34, cpos = idx % 34;
        const int gh = r - 1, gw = cpos - 1;
        uint4 v0 = make_uint4(0u, 0u, 0u, 0u), v1 = v0;
        if (((unsigned)gh < 32u) & ((unsigned)gw < 32u)) {
            const char* sp = (const char*)(src + (size_t)(gh * 32 + gw) * 16);
            v0 = *(const uint4*)sp;
            v1 = *(const uint4*)(sp + 16);
        }
        const int base = ((r - r0) * 34 + cpos) * 32;
        const int sw = (cpos & 4) << 2;
        *(uint4*)((char*)tile + (base ^ sw)) = v0;
        *(uint4*)((char*)tile + ((base + 16) ^ sw)) = v1;
    }
}

// ============ KMID: [0,2048) mix (LUT-load + coef + MFMA + S3 + dump); [2048,4096) conv stats ============
__global__ __launch_bounds__(256) void kmid(const signed char* __restrict__ h1c,
                                            const unsigned short* __restrict__ xsT,
                                            double* __restrict__ st,
                                            char* __restrict__ coefD,
                                            const unsigned short* __restrict__ lutG,
                                            const unsigned short* __restrict__ mixW,
                                            const unsigned short* __restrict__ convW) {
    __shared__ __align__(16) char smem[15232];
    const int tid = threadIdx.x, lane = tid & 63, wid = tid >> 6;
    if (blockIdx.x < 2048) {
        float* pad = (float*)smem;                              // 512
        unsigned short* lutL = (unsigned short*)(smem + 512);   // 640
        signed char* rawL = (signed char*)(smem + 2944);        // 4096
        unsigned short* coefL = (unsigned short*)(smem + 7040); // 8192
        const int pb = blockIdx.x & 3, gb = (blockIdx.x >> 2) & 15, tb = blockIdx.x >> 6;
        {
            const int ch = tid >> 3, o8 = (tid & 7) * 16;
            const int cab = (ch < 16) ? gb * 16 + ch : 256 + gb * 16 + (ch - 16);
            *(uint4*)(rawL + ch * 128 + o8) =
                *(const uint4*)(h1c + ((size_t)(tb * 512 + cab)) * 512 + pb * 128 + o8);
        }
        if (tid < 40)
            *(uint4*)((char*)lutL + tid * 16) = *(const uint4*)((const char*)lutG + gb * 640 + tid * 16);
        __syncthreads();
        {
            const int p = tid & 63, ds = tid >> 6;
            const int h2l = p >> 4, w2 = p & 15;
            unsigned pk[4][2];
            #pragma unroll
            for (int dd = 0; dd < 4; ++dd) {
                const int d = ds * 4 + dd;
                const int base = d * 128 + (2 * h2l) * 16 + w2;
                const int l0 = rawL[base], l1 = rawL[base + 16];
                const int q0 = rawL[2048 + base], q1 = rawL[2048 + base + 16];
                const unsigned short* lp = &lutL[d * 20];
                const unsigned hv[4] = { lp[l0 + l1],
                                         lp[5 + l0 - l1 + 2],
                                         lp[10 + q0 + q1 + 2],
                                         lp[15 + q0 - q1 + 2] };
                #pragma unroll
                for (int q = 0; q < 4; ++q) {
                    if (dd & 1) pk[q][dd >> 1] |= hv[q] << 16;
                    else        pk[q][dd >> 1] = hv[q];
                }
            }
            #pragma unroll
            for (int q = 0; q < 4; ++q) {
                const int slot = (((q & 1) * 2 + (ds >> 1)) ^ (p & 3));
                char* dst = (char*)coefL + (q >> 1) * 4096 + p * 64 + slot * 16 + (ds & 1) * 8;
                *(uint2*)dst = make_uint2(pk[q][0], pk[q][1]);
            }
        }
        short8 am[4];
        load_mix_frags(mixW, gb >> 2, lane, am);
        __syncthreads();
        {   // dump coefL slice to global (8 KB)
            char* base = coefD + ((size_t)(tb * 16 + gb)) * 32768 + pb * 4096;
            const int i = tid * 32;
            const int pair = i >> 12, loc = i & 4095;
            *(uint4*)(base + pair * 16384 + loc) = *(const uint4*)((const char*)coefL + i);
            *(uint4*)(base + pair * 16384 + loc + 16) = *(const uint4*)((const char*)coefL + i + 16);
        }
        const int o = lane & 15, g = lane >> 4;
        const int Pl = wid * 16 + o;
        f32x4 Mh[4];
        #pragma unroll
        for (int p = 0; p < 2; ++p) {
            const int slot = g ^ (o & 3);
            const short8 bf = *(const short8*)((const char*)coefL + p * 4096 + Pl * 64 + slot * 16);
            const f32x4 z = {0.f, 0.f, 0.f, 0.f};
            Mh[2 * p]     = __builtin_amdgcn_mfma_f32_16x16x32_bf16(am[2 * p], bf, z, 0, 0, 0);
            Mh[2 * p + 1] = __builtin_amdgcn_mfma_f32_16x16x32_bf16(am[2 * p + 1], bf, z, 0, 0, 0);
        }
        float s2x[4], se[4];
        #pragma unroll
        for (int r = 0; r < 4; ++r) {
            s2x[r] = 2.0f * Mh[0][r];
            se[r] = Mh[0][r] * Mh[0][r] + Mh[1][r] * Mh[1][r] + Mh[2][r] * Mh[2][r] + Mh[3][r] * Mh[3][r];
        }
        #pragma unroll
        for (int r = 0; r < 4; ++r)
            #pragma unroll
            for (int m = 1; m < 16; m <<= 1) {
                s2x[r] += __shfl_xor(s2x[r], m, 64);
                se[r]  += __shfl_xor(se[r], m, 64);
            }
        if ((lane & 15) == 0) {
            #pragma unroll
            for (int r = 0; r < 4; ++r) {
                pad[(wid * 16 + g * 4 + r) * 2]     = s2x[r];
                pad[(wid * 16 + g * 4 + r) * 2 + 1] = se[r];
            }
        }
        __syncthreads();
        if (tid < 32) {
            const int j = tid >> 1, s = tid & 1;
            const float tot = pad[(0 * 16 + j) * 2 + s] + pad[(1 * 16 + j) * 2 + s]
                            + pad[(2 * 16 + j) * 2 + s] + pad[(3 * 16 + j) * 2 + s];
            double* stw = st + (((((tb & 3) << 2) | pb)) * NST);
            atomicAdd(&stw[(s ? S3Q : S3S) + gb * 16 + j], (double)tot);
        }
    } else {
        const int bid = blockIdx.x - 2048;
        const int hb = bid & 3, gb = (bid >> 2) & 15, tb = bid >> 6;
        unsigned short* tile = (unsigned short*)smem;           // 10880
        float* pad = (float*)(smem + 10880);                    // 1024
        const unsigned short* src = xsT + (size_t)(tb * 16 + gb) * 1024 * 16;
        stage_rows(src, hb * 8, 10, tid, tile);
        short8 awc2[5], awc1;
        load_conv_frags(convW, lane, awc2, awc1);
        __syncthreads();
        float t1s[4] = {0, 0, 0, 0}, t1q[4] = {0, 0, 0, 0};
        float t2s[4] = {0, 0, 0, 0}, t2q[4] = {0, 0, 0, 0};
        #pragma unroll
        for (int ti = 0; ti < 4; ++ti) {
            const int lr = wid * 2 + (ti >> 1);
            const int w0 = (ti & 1) * 16;
            f32x4 a2v, a1v;
            conv_tile(tile, lane, lr, w0, awc2, awc1, a2v, a1v);
            #pragma unroll
            for (int r = 0; r < 4; ++r) {
                t1s[r] += a1v[r]; t1q[r] += a1v[r] * a1v[r];
                t2s[r] += a2v[r]; t2q[r] += a2v[r] * a2v[r];
            }
        }
        #pragma unroll
        for (int r = 0; r < 4; ++r)
            #pragma unroll
            for (int m = 1; m < 16; m <<= 1) {
                t1s[r] += __shfl_xor(t1s[r], m, 64);
                t1q[r] += __shfl_xor(t1q[r], m, 64);
                t2s[r] += __shfl_xor(t2s[r], m, 64);
                t2q[r] += __shfl_xor(t2q[r], m, 64);
            }
        if ((lane & 15) == 0) {
            const int G = lane >> 4;
            #pragma unroll
            for (int r = 0; r < 4; ++r) {
                const int oc = G * 4 + r;
                pad[(wid * 16 + oc) * 4 + 0] = t1s[r];
                pad[(wid * 16 + oc) * 4 + 1] = t1q[r];
                pad[(wid * 16 + oc) * 4 + 2] = t2s[r];
                pad[(wid * 16 + oc) * 4 + 3] = t2q[r];
            }
        }
        __syncthreads();
        if (tid < 64) {
            const int oc = tid >> 2, arr = tid & 3;
            const float vv = pad[(0 * 16 + oc) * 4 + arr] + pad[(1 * 16 + oc) * 4 + arr]
                           + pad[(2 * 16 + oc) * 4 + arr] + pad[(3 * 16 + oc) * 4 + arr];
            const int ch = gb * 16 + oc;
            const int off = (arr == 0 ? S4S : arr == 1 ? S4Q : arr == 2 ? S5S : S5Q) + ch;
            double* stw = st + (((((tb & 3) << 2) | hb)) * NST);
            atomicAdd(&stw[off], (double)vv);
        }
    }
}

// ============ KFIN: 1024 blocks (tb, gb, half) — 18-row tile + 8-h2-row coef slice ============
__global__ __launch_bounds__(256) void kfin(const unsigned short* __restrict__ xsT,
                                            const char* __restrict__ coefD,
                                            const double* __restrict__ st,
                                            const unsigned short* __restrict__ convW,
                                            const unsigned short* __restrict__ mixW,
                                            const float* __restrict__ g_inv, const float* __restrict__ b_inv,
                                            const float* __restrict__ g_c1, const float* __restrict__ b_c1,
                                            const float* __restrict__ g_c2, const float* __restrict__ b_c2,
                                            const float* __restrict__ conv1_b, const float* __restrict__ conv2_b,
                                            float* __restrict__ out) {
    __shared__ __align__(16) char smem[36224];
    const int tid = threadIdx.x, lane = tid & 63, wid = tid >> 6;
    const int hf = blockIdx.x & 1, gb = (blockIdx.x >> 1) & 15, tb = blockIdx.x >> 5;
    unsigned short* tile  = (unsigned short*)smem;            // 19584
    unsigned short* coefL = (unsigned short*)(smem + 19584);  // 16384
    float* PA3 = (float*)(smem + 35968);
    float* PA4 = PA3 + 16; float* PA5 = PA3 + 32; float* PK = PA3 + 48;
    if (tid < 16) {
        const int oc = tid, c = gb * 16 + oc;
        const double n3 = 32768.0;
        const double s3 = st_sum(st, S3S + c), q3 = st_sum(st, S3Q + c);
        const double m3 = s3 / n3, var3 = q3 / n3 - m3 * m3;
        const double a3 = (double)g_inv[c] / sqrt(var3 + EPS_);
        const double bias1 = (double)conv1_b[oc];
        const double s4r = st_sum(st, S4S + c), q4r = st_sum(st, S4Q + c);
        const double s4 = s4r + n3 * bias1;
        const double q4v = q4r + 2.0 * bias1 * s4r + n3 * bias1 * bias1;
        const double m4 = s4 / n3, var4 = q4v / n3 - m4 * m4;
        const double a4 = (double)g_c1[c] / sqrt(var4 + EPS_);
        const double bias2 = (double)conv2_b[oc];
        const double s5r = st_sum(st, S5S + c), q5r = st_sum(st, S5Q + c);
        const double s5 = s5r + n3 * bias2;
        const double q5v = q5r + 2.0 * bias2 * s5r + n3 * bias2 * bias2;
        const double m5 = s5 / n3, var5 = q5v / n3 - m5 * m5;
        const double a5 = (double)g_c2[c] / sqrt(var5 + EPS_);
        PA3[oc] = (float)a3; PA4[oc] = (float)a4; PA5[oc] = (float)a5;
        PK[oc] = (float)(((double)b_inv[c] - m3 * a3) + ((double)b_c1[c] - m4 * a4)
                       + ((double)b_c2[c] - m5 * a5) + a4 * bias1 + a5 * bias2);
    }
    stage_rows(xsT + (size_t)(tb * 16 + gb) * 1024 * 16, hf * 16, 18, tid, tile);
    {
        const char* dump = coefD + ((size_t)(tb * 16 + gb)) * 32768 + hf * 8192;
        #pragma unroll
        for (int i = 0; i < 4; ++i)
            *(uint4*)((char*)coefL + i * 4096 + tid * 16) =
                *(const uint4*)(dump + (i >> 1) * 16384 + (i & 1) * 4096 + tid * 16);
    }
    short8 am[4], awc2[5], awc1;
    load_mix_frags(mixW, gb >> 2, lane, am);
    load_conv_frags(convW, lane, awc2, awc1);
    __syncthreads();
    const int G = lane >> 4, n = lane & 15;
    float fA3[4], fA4[4], fA5[4], fK[4];
    #pragma unroll
    for (int r = 0; r < 4; ++r) {
        const int oc = G * 4 + r;
        fA3[r] = PA3[oc]; fA4[r] = PA4[oc]; fA5[r] = PA5[oc]; fK[r] = PK[oc];
    }
    const float sw = (n & 1) ? -1.0f : 1.0f;
    #pragma unroll
    for (int hh2 = 0; hh2 < 2; ++hh2) {
        f32x4 Mh[4];
        {
            const int o = lane & 15, g = lane >> 4;
            const int Pl = (wid * 2 + hh2) * 16 + o;
            #pragma unroll
            for (int p = 0; p < 2; ++p) {
                const int slot = g ^ (o & 3);
                const short8 bf = *(const short8*)((const char*)coefL + p * 8192 + Pl * 64 + slot * 16);
                const f32x4 z = {0.f, 0.f, 0.f, 0.f};
                Mh[2 * p]     = __builtin_amdgcn_mfma_f32_16x16x32_bf16(am[2 * p], bf, z, 0, 0, 0);
                Mh[2 * p + 1] = __builtin_amdgcn_mfma_f32_16x16x32_bf16(am[2 * p + 1], bf, z, 0, 0, 0);
            }
        }
        #pragma unroll
        for (int w0h = 0; w0h < 2; ++w0h) {
            const int src = (lane & 48) + w0h * 8 + (n >> 1);
            float ms[4][4];
            #pragma unroll
            for (int q = 0; q < 4; ++q)
                #pragma unroll
                for (int r = 0; r < 4; ++r) ms[q][r] = __shfl(Mh[q][r], src, 64);
            #pragma unroll
            for (int hrow = 0; hrow < 2; ++hrow) {
                const float sh = hrow ? -1.0f : 1.0f;
                const int hl = wid * 4 + hh2 * 2 + hrow;
                const int hglob = hf * 16 + hl;
                const int w0 = w0h * 16;
                f32x4 a2v, a1v;
                conv_tile(tile, lane, hl, w0, awc2, awc1, a2v, a1v);
                #pragma unroll
                for (int r = 0; r < 4; ++r) {
                    const float rec = 0.5f * ((ms[0][r] + sh * ms[1][r]) + sw * (ms[2][r] + sh * ms[3][r]));
                    const int oc = G * 4 + r;
                    const size_t ai = ((size_t)(tb * 256 + gb * 16 + oc)) * 1024 + (size_t)hglob * 32 + w0 + n;
                    out[ai] = fA3[r] * rec + fA4[r] * a1v[r] + fA5[r] * a2v[r] + fK[r];
                }
            }
        }
    }
}

extern "C" void kernel_launch(void* const* d_in, const int* in_sizes, int n_in,
                              void* d_out, int out_size, void* d_ws, size_t ws_size,
                              hipStream_t stream) {
    const float* x        = (const float*)d_in[0];
    const float* haar_w   = (const float*)d_in[1];
    const float* conv1_w  = (const float*)d_in[2];
    const float* conv1_b  = (const float*)d_in[3];
    const float* conv2_w  = (const float*)d_in[4];
    const float* conv2_b  = (const float*)d_in[5];
    const float* g_fwd    = (const float*)d_in[6];
    const float* b_fwd    = (const float*)d_in[7];
    const float* g_mul    = (const float*)d_in[8];
    const float* b_mul    = (const float*)d_in[9];
    const float* g_inv    = (const float*)d_in[10];
    const float* b_inv    = (const float*)d_in[11];
    const float* g_c1     = (const float*)d_in[12];
    const float* b_c1     = (const float*)d_in[13];
    const float* g_c2     = (const float*)d_in[14];
    const float* b_c2     = (const float*)d_in[15];
    float* out = (float*)d_out;

    char* ws = (char*)d_ws;
    unsigned short* xsT = (unsigned short*)(ws + XST_OFF);
    signed char* h1c    = (signed char*)(ws + H1C_OFF);
    char* coefD         = ws + COEF_OFF;
    double* st          = (double*)(ws + ST_OFF);
    unsigned short* convW = (unsigned short*)(ws + WTAB_OFF);
    unsigned short* mixW  = (unsigned short*)(ws + WTAB_OFF + 6144);
    int* hist           = (int*)(ws + HIST_OFF);
    unsigned short* lutG = (unsigned short*)(ws + LUTG_OFF);

    k1_lif<<<dim3(512), dim3(256), 0, stream>>>(x, xsT, h1c, hist, st,
                                                conv1_w, conv2_w, haar_w, convW, mixW);
    klut<<<dim3(16), dim3(256), 0, stream>>>(hist, g_fwd, b_fwd, g_mul, b_mul, lutG);
    kmid<<<dim3(4096), dim3(256), 0, stream>>>(h1c, xsT, st, coefD, lutG, mixW, convW);
    kfin<<<dim3(1024), dim3(256), 0, stream>>>(xsT, coefD, st, convW, mixW,
                                               g_inv, b_inv, g_c1, b_c1, g_c2, b_c2,
                                               conv1_b, conv2_b, out);
}